// Round 2
// baseline (401.193 us; speedup 1.0000x reference)
//
#include <hip/hip_runtime.h>

#define N_PTS 20000
#define DIMS  128
#define A_CNT 1024
#define KNEG  10
#define NTILES 157             // ceil(20000/128)
#define NCHUNK (NTILES * 16)   // 2512 chunk-of-8 minima per (side, anchor)
#define BIGV  1e18f

// ---------------------------------------------------------------------------
// Kernel A: for each (side, anchor-group, point-tile) compute the 128x128 L1
// distance tile (8x8 register blocking) and emit per-anchor minima over each
// 8-point chunk to workspace. Pure fp32, exact.
// LDS: sA[32][128] (16KB) + sP[32][140] (17.5KB, swizzled cols) = 33.5KB -> 4 blk/CU.
// __launch_bounds__(256,2): 256-VGPR unified budget so the 64 accumulators stay
// in architectural VGPRs (with (256,4) the allocator split 64 VGPR + 64 AGPR and
// round-tripped via v_accvgpr_* — 2.4x VALU inflation, measured round 1).
// ---------------------------------------------------------------------------
__global__ __launch_bounds__(256, 2)
void dist_min_kernel(const float* __restrict__ out1, const float* __restrict__ out2,
                     const int* __restrict__ anchor1, const int* __restrict__ anchor2,
                     float* __restrict__ minOut) {
    __shared__ float sA[32][128];
    __shared__ float sP[32][140];   // cols swizzled: col = p + (p>>5)*4

    const int tile = blockIdx.x;    // 0..156
    const int ag   = blockIdx.y;    // 0..7
    const int side = blockIdx.z;    // 0..1

    const float* aData = side ? out2 : out1;
    const float* pData = side ? out1 : out2;
    const int*   aIdx  = side ? anchor2 : anchor1;

    const int tid = threadIdx.x;
    const int tx = tid & 15;        // point chunk within tile (8 pts)
    const int ty = tid >> 4;        // anchor group-of-8 within tile

    // staging role: each thread loads 16 dims (half a BK-chunk) of one row
    const int rowHalf = tid >> 1;          // 0..127
    const int halfOff = (tid & 1) * 16;    // 0 or 16
    const float* aptr = aData + (size_t)aIdx[ag * 128 + rowHalf] * DIMS;
    const int prow = tile * 128 + rowHalf;
    const bool pvalid = prow < N_PTS;
    const float* pptr = pData + (size_t)prow * DIMS;
    const int pcol = rowHalf + (rowHalf >> 5) * 4;   // swizzled column

    float acc[8][8];
#pragma unroll
    for (int i = 0; i < 8; ++i)
#pragma unroll
        for (int j = 0; j < 8; ++j) acc[i][j] = 0.f;

    const int ty8 = ty * 8;
    const int pbase = tx * 8 + (tx >> 2) * 4;        // swizzled read base

    for (int bk = 0; bk < 4; ++bk) {
        // global loads first (overlap with previous compute finishing)
        float4 av[4], pv[4];
        const float4* ap4 = (const float4*)(aptr + bk * 32 + halfOff);
        const float4* pp4 = (const float4*)(pptr + bk * 32 + halfOff);
#pragma unroll
        for (int j = 0; j < 4; ++j) {
            av[j] = ap4[j];
            pv[j] = pvalid ? pp4[j] : make_float4(BIGV, BIGV, BIGV, BIGV);
        }
        __syncthreads();   // previous compute phase done reading LDS
#pragma unroll
        for (int j = 0; j < 4; ++j) {
            const int d = halfOff + j * 4;
            sA[d + 0][rowHalf] = av[j].x;  sA[d + 1][rowHalf] = av[j].y;
            sA[d + 2][rowHalf] = av[j].z;  sA[d + 3][rowHalf] = av[j].w;
            sP[d + 0][pcol]    = pv[j].x;  sP[d + 1][pcol]    = pv[j].y;
            sP[d + 2][pcol]    = pv[j].z;  sP[d + 3][pcol]    = pv[j].w;
        }
        __syncthreads();

#pragma unroll 4
        for (int dd = 0; dd < 32; ++dd) {
            const float4 a0 = *(const float4*)&sA[dd][ty8];
            const float4 a1 = *(const float4*)&sA[dd][ty8 + 4];
            const float4 p0 = *(const float4*)&sP[dd][pbase];
            const float4 p1 = *(const float4*)&sP[dd][pbase + 4];
#define ROWOP(i, AV) \
            acc[i][0] += fabsf(AV - p0.x); acc[i][1] += fabsf(AV - p0.y); \
            acc[i][2] += fabsf(AV - p0.z); acc[i][3] += fabsf(AV - p0.w); \
            acc[i][4] += fabsf(AV - p1.x); acc[i][5] += fabsf(AV - p1.y); \
            acc[i][6] += fabsf(AV - p1.z); acc[i][7] += fabsf(AV - p1.w);
            ROWOP(0, a0.x) ROWOP(1, a0.y) ROWOP(2, a0.z) ROWOP(3, a0.w)
            ROWOP(4, a1.x) ROWOP(5, a1.y) ROWOP(6, a1.z) ROWOP(7, a1.w)
#undef ROWOP
        }
    }

    // per-anchor minimum over this thread's 8-point chunk
    const int aBase = ag * 128 + ty8;
    const size_t outBase = (size_t)side * A_CNT * NCHUNK;
#pragma unroll
    for (int i = 0; i < 8; ++i) {
        float m = fminf(fminf(fminf(acc[i][0], acc[i][1]), fminf(acc[i][2], acc[i][3])),
                        fminf(fminf(acc[i][4], acc[i][5]), fminf(acc[i][6], acc[i][7])));
        minOut[outBase + (size_t)(aBase + i) * NCHUNK + tile * 16 + tx] = m;
    }
}

// ---------------------------------------------------------------------------
// branchless sorted insert into ascending top-10
// ---------------------------------------------------------------------------
__device__ __forceinline__ void insert10(float (&t)[10], float v) {
    if (v < t[9]) {
#pragma unroll
        for (int i = 9; i >= 1; --i) t[i] = fminf(t[i], fmaxf(t[i - 1], v));
        t[0] = fminf(t[0], v);
    }
}

__device__ __forceinline__ void mergeTop10(float (&t)[10]) {
    for (int s = 1; s < 64; s <<= 1) {
        float o[10];
#pragma unroll
        for (int k = 0; k < 10; ++k) o[k] = __shfl_xor(t[k], s, 64);
#pragma unroll
        for (int k = 0; k < 10; ++k) insert10(t, o[k]);
    }
}

// ---------------------------------------------------------------------------
// Kernel B: one wave per (side, anchor). Find m10 = 10th smallest chunk-min,
// identify the (>=10, ~10) chunks with min <= m10 — these provably contain all
// top-10 values — recompute those distances exactly, select top-10, loss.
// ---------------------------------------------------------------------------
__global__ __launch_bounds__(64)
void select_kernel(const float* __restrict__ out1, const float* __restrict__ out2,
                   const int* __restrict__ anchor1, const int* __restrict__ anchor2,
                   const float* __restrict__ minIn, float* __restrict__ out) {
    const int bid = blockIdx.x;          // 0..2047
    const int side = bid >> 10;
    const int ai = bid & 1023;
    const int lane = threadIdx.x;

    const float* aData = side ? out2 : out1;
    const float* pData = side ? out1 : out2;
    const int*   aIdx  = side ? anchor2 : anchor1;

    __shared__ float aRow[DIMS];
    __shared__ int candCount;
    __shared__ int candList[32];

    // stage anchor row
    const int arow = aIdx[ai];
    const float2 a2v = ((const float2*)(aData + (size_t)arow * DIMS))[lane];
    aRow[2 * lane] = a2v.x;  aRow[2 * lane + 1] = a2v.y;
    if (lane == 0) candCount = 0;
    __syncthreads();

    // Dm = L1(out1[anchor1[ai]], out2[anchor2[ai]]) + GAMMA  (shared by both sides)
    const int r1 = anchor1[ai], r2 = anchor2[ai];
    const float2 x1 = ((const float2*)(out1 + (size_t)r1 * DIMS))[lane];
    const float2 x2 = ((const float2*)(out2 + (size_t)r2 * DIMS))[lane];
    float dm = fabsf(x1.x - x2.x) + fabsf(x1.y - x2.y);
#pragma unroll
    for (int s = 1; s < 64; s <<= 1) dm += __shfl_xor(dm, s, 64);
    dm += 1.0f;   // GAMMA

    // load chunk minima (coalesced), find 10th smallest
    const float* mbase = minIn + ((size_t)side * A_CNT + ai) * NCHUNK;
    float mv[40];
#pragma unroll
    for (int j = 0; j < 40; ++j) {
        const int c = j * 64 + lane;
        mv[j] = (c < NCHUNK) ? mbase[c] : BIGV;
    }
    float t[10];
#pragma unroll
    for (int k = 0; k < 10; ++k) t[k] = BIGV;
#pragma unroll
    for (int j = 0; j < 40; ++j) insert10(t, mv[j]);
    mergeTop10(t);
    const float m10 = t[9];

    // compact qualifying chunk indices
    for (int j = 0; j < 40; ++j) {
        const int c = j * 64 + lane;
        if (c < NCHUNK && mv[j] <= m10) {
            const int pos = atomicAdd(&candCount, 1);
            if (pos < 32) candList[pos] = c;
        }
    }
    __syncthreads();
    const int cc = min(candCount, 32);

    // exact recompute of candidate distances; top-10 of values
    float t2[10];
#pragma unroll
    for (int k = 0; k < 10; ++k) t2[k] = BIGV;

    for (int g = 0; g * 8 < cc; ++g) {
        const int slot = g * 8 + (lane >> 3);
        if (slot < cc) {
            const int c = candList[slot];
            const int pr = c * 8 + (lane & 7);
            if (pr < N_PTS) {
                const float4* p4 = (const float4*)(pData + (size_t)pr * DIMS);
                float s0 = 0.f, s1 = 0.f, s2 = 0.f, s3 = 0.f;
#pragma unroll
                for (int q = 0; q < 32; ++q) {
                    const float4 pv = p4[q];
                    const float4 av = *(const float4*)&aRow[q * 4];
                    s0 += fabsf(av.x - pv.x);
                    s1 += fabsf(av.y - pv.y);
                    s2 += fabsf(av.z - pv.z);
                    s3 += fabsf(av.w - pv.w);
                }
                insert10(t2, (s0 + s1) + (s2 + s3));
            }
        }
    }
    mergeTop10(t2);

    if (lane == 0) {
        float sum = 0.f;
#pragma unroll
        for (int k = 0; k < 10; ++k) sum += fmaxf(dm - t2[k], 0.f);
        atomicAdd(out, sum * (1.0f / (A_CNT * KNEG)));
    }
}

extern "C" void kernel_launch(void* const* d_in, const int* in_sizes, int n_in,
                              void* d_out, int out_size, void* d_ws, size_t ws_size,
                              hipStream_t stream) {
    const float* out1    = (const float*)d_in[0];
    const float* out2    = (const float*)d_in[1];
    const int*   anchor1 = (const int*)d_in[2];
    const int*   anchor2 = (const int*)d_in[3];
    float* out = (float*)d_out;
    float* minbuf = (float*)d_ws;   // 2*1024*2512 floats = 20.6 MB

    hipMemsetAsync(out, 0, sizeof(float), stream);

    dim3 gridA(NTILES, 8, 2);
    hipLaunchKernelGGL(dist_min_kernel, gridA, dim3(256), 0, stream,
                       out1, out2, anchor1, anchor2, minbuf);
    hipLaunchKernelGGL(select_kernel, dim3(2048), dim3(64), 0, stream,
                       out1, out2, anchor1, anchor2, minbuf, out);
}

// Round 3
// 367.150 us; speedup vs baseline: 1.0927x; 1.0927x over previous
//
#include <hip/hip_runtime.h>
#include <hip/hip_fp16.h>

#define N_PTS 20000
#define DIMS  128
#define A_CNT 1024
#define KNEG  10
#define NTILES 157             // ceil(20000/128)
#define NCHUNK (NTILES * 16)   // 2512 chunk-of-8 minima per (side, anchor)
#define BIGV  1e18f
#define EPS_APPROX 1.0f        // conservative bound on |d_fp16 - d_fp32| (analysis: <0.35)
#define PAD_H2 0x77537753u     // half2(30000, 30000) padding for tail points
#define CAND_CAP 96

typedef _Float16 half2_t __attribute__((ext_vector_type(2)));

__device__ __forceinline__ half2_t u2h(unsigned int u) { return __builtin_bit_cast(half2_t, u); }

// ---------------------------------------------------------------------------
// Prologue: fp32 -> fp16 conversion (RN), once per side. ~10MB total, trivial.
// ---------------------------------------------------------------------------
__global__ void cvt_half_kernel(const float* __restrict__ src, __half2* __restrict__ dst, int n4) {
    const int stride = gridDim.x * blockDim.x;
    for (int i = blockIdx.x * blockDim.x + threadIdx.x; i < n4; i += stride) {
        const float4 v = ((const float4*)src)[i];
        dst[2 * i]     = __floats2half2_rn(v.x, v.y);
        dst[2 * i + 1] = __floats2half2_rn(v.z, v.w);
    }
}

// ---------------------------------------------------------------------------
// Kernel A (fp16): 128 anchors x 128 points per block, 8x8 per thread.
// Per dim-pair q: d = pk_sub, |d| = one v_and_b32, acc = v_dot2_f32_f16
//   -> 3 VALU per 2 elements (vs ~4.6/elem measured for the fp32 path).
// LDS: sA2[16][128] uints (8KB) + sP2[16][192] swizzled (12KB) = 20KB.
// sP swizzle col = p + 4*(p>>3): blocks of 8 half2 stay 16B-aligned, the 16
// b128 readers hit 16 distinct even bank offsets -> worst 2-way (free).
// Emits per-anchor chunk-of-8 minima (fp16) to workspace; exact fp32
// re-verification of candidates happens in select_kernel.
// ---------------------------------------------------------------------------
__global__ __launch_bounds__(256, 2)
void dist_min_h2(const __half* __restrict__ hp1, const __half* __restrict__ hp2,
                 const int* __restrict__ anchor1, const int* __restrict__ anchor2,
                 __half* __restrict__ minOut) {
    __shared__ unsigned int sA2[16 * 128];
    __shared__ unsigned int sP2[16 * 192];

    const int tile = blockIdx.x;    // 0..156
    const int ag   = blockIdx.y;    // 0..7
    const int side = blockIdx.z;    // 0..1

    const __half* aData = side ? hp2 : hp1;
    const __half* pData = side ? hp1 : hp2;
    const int*    aIdx  = side ? anchor2 : anchor1;

    const int tid = threadIdx.x;
    const int tx = tid & 15;        // point chunk (8 pts)
    const int ty = tid >> 4;        // anchor group-of-8

    // staging role: each thread loads 16 dims (= 8 half2 words) of one row
    const int rowHalf = tid >> 1;          // 0..127
    const int qbase   = (tid & 1) * 8;     // half2-word offset within bk-chunk
    const unsigned int* aRowU =
        (const unsigned int*)(aData + (size_t)aIdx[ag * 128 + rowHalf] * DIMS);
    const int prow = tile * 128 + rowHalf;
    const bool pvalid = prow < N_PTS;
    const unsigned int* pRowU = (const unsigned int*)(pData + (size_t)prow * DIMS);
    const int pwcol = rowHalf + 4 * (rowHalf >> 3);   // swizzled write col

    float acc[8][8];
#pragma unroll
    for (int i = 0; i < 8; ++i)
#pragma unroll
        for (int j = 0; j < 8; ++j) acc[i][j] = 0.f;

    const int ty8 = ty * 8;
    const int px12 = tx * 12;       // swizzled read base (block t starts at 12t)
    const half2_t one2 = {(_Float16)1.0f, (_Float16)1.0f};

    for (int bk = 0; bk < 4; ++bk) {
        // global loads (8 half2 words = 32B per thread, per matrix)
        const uint4* ap4 = (const uint4*)(aRowU + bk * 16 + qbase);
        const uint4* pp4 = (const uint4*)(pRowU + bk * 16 + qbase);
        uint4 av0 = ap4[0], av1 = ap4[1];
        uint4 pv0, pv1;
        if (pvalid) { pv0 = pp4[0]; pv1 = pp4[1]; }
        else { pv0 = pv1 = make_uint4(PAD_H2, PAD_H2, PAD_H2, PAD_H2); }

        __syncthreads();   // previous compute phase done reading LDS
        sA2[(qbase + 0) * 128 + rowHalf] = av0.x;
        sA2[(qbase + 1) * 128 + rowHalf] = av0.y;
        sA2[(qbase + 2) * 128 + rowHalf] = av0.z;
        sA2[(qbase + 3) * 128 + rowHalf] = av0.w;
        sA2[(qbase + 4) * 128 + rowHalf] = av1.x;
        sA2[(qbase + 5) * 128 + rowHalf] = av1.y;
        sA2[(qbase + 6) * 128 + rowHalf] = av1.z;
        sA2[(qbase + 7) * 128 + rowHalf] = av1.w;
        sP2[(qbase + 0) * 192 + pwcol] = pv0.x;
        sP2[(qbase + 1) * 192 + pwcol] = pv0.y;
        sP2[(qbase + 2) * 192 + pwcol] = pv0.z;
        sP2[(qbase + 3) * 192 + pwcol] = pv0.w;
        sP2[(qbase + 4) * 192 + pwcol] = pv1.x;
        sP2[(qbase + 5) * 192 + pwcol] = pv1.y;
        sP2[(qbase + 6) * 192 + pwcol] = pv1.z;
        sP2[(qbase + 7) * 192 + pwcol] = pv1.w;
        __syncthreads();

#pragma unroll 4
        for (int q = 0; q < 16; ++q) {
            const uint4* A4 = (const uint4*)&sA2[q * 128 + ty8];
            const uint4 Aa = A4[0], Ab = A4[1];
            const uint4* P4 = (const uint4*)&sP2[q * 192 + px12];
            const uint4 Pa = P4[0], Pb = P4[1];
            const half2_t a2[8] = {u2h(Aa.x), u2h(Aa.y), u2h(Aa.z), u2h(Aa.w),
                                   u2h(Ab.x), u2h(Ab.y), u2h(Ab.z), u2h(Ab.w)};
            const half2_t p2[8] = {u2h(Pa.x), u2h(Pa.y), u2h(Pa.z), u2h(Pa.w),
                                   u2h(Pb.x), u2h(Pb.y), u2h(Pb.z), u2h(Pb.w)};
#pragma unroll
            for (int i = 0; i < 8; ++i)
#pragma unroll
                for (int j = 0; j < 8; ++j) {
                    const half2_t d = a2[i] - p2[j];
                    const unsigned int ud = __builtin_bit_cast(unsigned int, d) & 0x7FFF7FFFu;
                    acc[i][j] = __builtin_amdgcn_fdot2(u2h(ud), one2, acc[i][j], false);
                }
        }
    }

    // per-anchor minimum over this thread's 8-point chunk (approx values)
    const int aBase = ag * 128 + ty8;
    const size_t outBase = (size_t)side * A_CNT * NCHUNK;
#pragma unroll
    for (int i = 0; i < 8; ++i) {
        float m = fminf(fminf(fminf(acc[i][0], acc[i][1]), fminf(acc[i][2], acc[i][3])),
                        fminf(fminf(acc[i][4], acc[i][5]), fminf(acc[i][6], acc[i][7])));
        m = fminf(m, 60000.f);   // keep finite in fp16 (pad chunks)
        minOut[outBase + (size_t)(aBase + i) * NCHUNK + tile * 16 + tx] = __float2half(m);
    }
}

// ---------------------------------------------------------------------------
// branchless sorted insert into ascending top-10
// ---------------------------------------------------------------------------
__device__ __forceinline__ void insert10(float (&t)[10], float v) {
    if (v < t[9]) {
#pragma unroll
        for (int i = 9; i >= 1; --i) t[i] = fminf(t[i], fmaxf(t[i - 1], v));
        t[0] = fminf(t[0], v);
    }
}

__device__ __forceinline__ void mergeTop10(float (&t)[10]) {
    for (int s = 1; s < 64; s <<= 1) {
        float o[10];
#pragma unroll
        for (int k = 0; k < 10; ++k) o[k] = __shfl_xor(t[k], s, 64);
#pragma unroll
        for (int k = 0; k < 10; ++k) insert10(t, o[k]);
    }
}

// ---------------------------------------------------------------------------
// Kernel B: one wave per (side, anchor). m10 = 10th smallest approx chunk-min.
// Candidates: chunks with min <= m10 + 2*EPS (provably a superset of the true
// top-10 under |approx-exact| <= EPS). Recompute candidates EXACTLY in fp32
// from the original arrays, top-10, loss. Result is exact.
// ---------------------------------------------------------------------------
__global__ __launch_bounds__(64)
void select_kernel(const float* __restrict__ out1, const float* __restrict__ out2,
                   const int* __restrict__ anchor1, const int* __restrict__ anchor2,
                   const __half* __restrict__ minIn, float* __restrict__ out) {
    const int bid = blockIdx.x;          // 0..2047
    const int side = bid >> 10;
    const int ai = bid & 1023;
    const int lane = threadIdx.x;

    const float* aData = side ? out2 : out1;
    const float* pData = side ? out1 : out2;
    const int*   aIdx  = side ? anchor2 : anchor1;

    __shared__ float aRow[DIMS];
    __shared__ int candCount;
    __shared__ int candList[CAND_CAP];

    // stage anchor row (exact fp32)
    const int arow = aIdx[ai];
    const float2 a2v = ((const float2*)(aData + (size_t)arow * DIMS))[lane];
    aRow[2 * lane] = a2v.x;  aRow[2 * lane + 1] = a2v.y;
    if (lane == 0) candCount = 0;
    __syncthreads();

    // Dm = L1(out1[anchor1[ai]], out2[anchor2[ai]]) + GAMMA
    const int r1 = anchor1[ai], r2 = anchor2[ai];
    const float2 x1 = ((const float2*)(out1 + (size_t)r1 * DIMS))[lane];
    const float2 x2 = ((const float2*)(out2 + (size_t)r2 * DIMS))[lane];
    float dm = fabsf(x1.x - x2.x) + fabsf(x1.y - x2.y);
#pragma unroll
    for (int s = 1; s < 64; s <<= 1) dm += __shfl_xor(dm, s, 64);
    dm += 1.0f;   // GAMMA

    // load approx chunk minima, find 10th smallest
    const __half* mbase = minIn + ((size_t)side * A_CNT + ai) * NCHUNK;
    float mv[40];
#pragma unroll
    for (int j = 0; j < 40; ++j) {
        const int c = j * 64 + lane;
        mv[j] = (c < NCHUNK) ? __half2float(mbase[c]) : BIGV;
    }
    float t[10];
#pragma unroll
    for (int k = 0; k < 10; ++k) t[k] = BIGV;
#pragma unroll
    for (int j = 0; j < 40; ++j) insert10(t, mv[j]);
    mergeTop10(t);
    const float thr = t[9] + 2.0f * EPS_APPROX;

    // compact qualifying chunk indices
    for (int j = 0; j < 40; ++j) {
        const int c = j * 64 + lane;
        if (c < NCHUNK && mv[j] <= thr) {
            const int pos = atomicAdd(&candCount, 1);
            if (pos < CAND_CAP) candList[pos] = c;
        }
    }
    __syncthreads();
    const int cc = min(candCount, CAND_CAP);

    // exact fp32 recompute of candidate distances; top-10 of values
    float t2[10];
#pragma unroll
    for (int k = 0; k < 10; ++k) t2[k] = BIGV;

    for (int g = 0; g * 8 < cc; ++g) {
        const int slot = g * 8 + (lane >> 3);
        if (slot < cc) {
            const int c = candList[slot];
            const int pr = c * 8 + (lane & 7);
            if (pr < N_PTS) {
                const float4* p4 = (const float4*)(pData + (size_t)pr * DIMS);
                float s0 = 0.f, s1 = 0.f, s2 = 0.f, s3 = 0.f;
#pragma unroll
                for (int q = 0; q < 32; ++q) {
                    const float4 pv = p4[q];
                    const float4 av = *(const float4*)&aRow[q * 4];
                    s0 += fabsf(av.x - pv.x);
                    s1 += fabsf(av.y - pv.y);
                    s2 += fabsf(av.z - pv.z);
                    s3 += fabsf(av.w - pv.w);
                }
                insert10(t2, (s0 + s1) + (s2 + s3));
            }
        }
    }
    mergeTop10(t2);

    if (lane == 0) {
        float sum = 0.f;
#pragma unroll
        for (int k = 0; k < 10; ++k) sum += fmaxf(dm - t2[k], 0.f);
        atomicAdd(out, sum * (1.0f / (A_CNT * KNEG)));
    }
}

extern "C" void kernel_launch(void* const* d_in, const int* in_sizes, int n_in,
                              void* d_out, int out_size, void* d_ws, size_t ws_size,
                              hipStream_t stream) {
    const float* out1    = (const float*)d_in[0];
    const float* out2    = (const float*)d_in[1];
    const int*   anchor1 = (const int*)d_in[2];
    const int*   anchor2 = (const int*)d_in[3];
    float* out = (float*)d_out;

    // ws layout: h1 (5.12MB) | h2 (5.12MB) | minbuf fp16 (10.29MB) = 20.53MB
    __half* h1 = (__half*)d_ws;
    __half* h2 = h1 + (size_t)N_PTS * DIMS;
    __half* minbuf = h2 + (size_t)N_PTS * DIMS;

    hipMemsetAsync(out, 0, sizeof(float), stream);

    const int n4 = N_PTS * DIMS / 4;   // 640000 float4 per side
    hipLaunchKernelGGL(cvt_half_kernel, dim3(512), dim3(256), 0, stream, out1, (__half2*)h1, n4);
    hipLaunchKernelGGL(cvt_half_kernel, dim3(512), dim3(256), 0, stream, out2, (__half2*)h2, n4);

    dim3 gridA(NTILES, 8, 2);
    hipLaunchKernelGGL(dist_min_h2, gridA, dim3(256), 0, stream,
                       h1, h2, anchor1, anchor2, minbuf);
    hipLaunchKernelGGL(select_kernel, dim3(2048), dim3(64), 0, stream,
                       out1, out2, anchor1, anchor2, minbuf, out);
}